// Round 1
// baseline (195.195 us; speedup 1.0000x reference)
//
#include <hip/hip_runtime.h>
#include <hip/hip_bf16.h>

// Ragged (values, offsets) -> dense [num_rows, 32] fp32.
// Output-centric: out[row][col] = col < len(row) ? values[offsets[row]+col] : 0
// One thread per output float4 (8 threads per row, DIM=32).
// Every output element is written exactly once -> no zero-init pass needed.

#define DIM 32

__global__ __launch_bounds__(256) void ragged_to_dense_kernel(
    const float* __restrict__ values,
    const int*   __restrict__ offsets,
    float*       __restrict__ out,
    int num_rows,
    int total_values)
{
    int g = blockIdx.x * blockDim.x + threadIdx.x;   // one float4 of output
    int row = g >> 3;                                 // 8 float4s per row (DIM=32)
    if (row >= num_rows) return;
    int c0 = (g & 7) << 2;                            // first col of this quad

    int start = offsets[row];
    int end   = (row + 1 < num_rows) ? offsets[row + 1] : total_values;
    int len   = end - start;

    const float* src = values + start + c0;
    float4 v;
    v.x = (c0 + 0 < len) ? src[0] : 0.0f;
    v.y = (c0 + 1 < len) ? src[1] : 0.0f;
    v.z = (c0 + 2 < len) ? src[2] : 0.0f;
    v.w = (c0 + 3 < len) ? src[3] : 0.0f;

    reinterpret_cast<float4*>(out)[g] = v;
}

extern "C" void kernel_launch(void* const* d_in, const int* in_sizes, int n_in,
                              void* d_out, int out_size, void* d_ws, size_t ws_size,
                              hipStream_t stream) {
    const float* values  = (const float*)d_in[0];
    const int*   offsets = (const int*)d_in[1];
    // d_in[2] is `dimension` (scalar 32) — DIM hard-coded.
    float* out = (float*)d_out;

    int total_values = in_sizes[0];     // 17,301,504
    int num_rows     = in_sizes[1];     // 1,048,576
    int n_quads      = num_rows * (DIM / 4);   // one thread per float4

    const int block = 256;
    int grid = (n_quads + block - 1) / block;
    ragged_to_dense_kernel<<<grid, block, 0, stream>>>(
        values, offsets, out, num_rows, total_values);
}

// Round 2
// 193.530 us; speedup vs baseline: 1.0086x; 1.0086x over previous
//
#include <hip/hip_runtime.h>
#include <hip/hip_bf16.h>

// Ragged (values, offsets) -> dense [num_rows, 32] fp32.
// Output-centric: out[row][col] = col < len(row) ? values[offsets[row]+col] : 0
// One thread per output float4 (8 threads per row, DIM=32).
// Every output element is written exactly once -> no zero-init pass needed
// (required anyway: d_out is 0xAA-poisoned before every timed launch).
//
// Traffic floor: 134 MB write + 69 MB values read + 4 MB offsets read
// ~= 207 MB @ ~6.9 TB/s ~= 30 us. Fast path: full-quad float4 load (most
// quads are either fully in-range or fully out given len cycles 1..32).

#define DIM 32

__global__ __launch_bounds__(256) void ragged_to_dense_kernel(
    const float* __restrict__ values,
    const int*   __restrict__ offsets,
    float*       __restrict__ out,
    int num_rows,
    int total_values)
{
    int g = blockIdx.x * blockDim.x + threadIdx.x;   // one float4 of output
    int row = g >> 3;                                 // 8 float4s per row (DIM=32)
    if (row >= num_rows) return;
    int c0 = (g & 7) << 2;                            // first col of this quad

    int start = offsets[row];
    int end   = (row + 1 < num_rows) ? offsets[row + 1] : total_values;
    int len   = end - start;

    float4 v = make_float4(0.0f, 0.0f, 0.0f, 0.0f);
    const float* src = values + start + c0;
    if (c0 + 4 <= len) {
        // Quad fully in range: one 16B vector load.
        v = *reinterpret_cast<const float4*>(src);
    } else if (c0 < len) {
        // Partial tail quad: predicated scalar loads.
        v.x = src[0];
        if (c0 + 1 < len) v.y = src[1];
        if (c0 + 2 < len) v.z = src[2];
        // c0+3 < len impossible here (would be the full-quad path)
    }
    // else: quad entirely past the row end -> zeros.

    reinterpret_cast<float4*>(out)[g] = v;
}

extern "C" void kernel_launch(void* const* d_in, const int* in_sizes, int n_in,
                              void* d_out, int out_size, void* d_ws, size_t ws_size,
                              hipStream_t stream) {
    const float* values  = (const float*)d_in[0];
    const int*   offsets = (const int*)d_in[1];
    // d_in[2] is `dimension` (scalar 32) — DIM hard-coded.
    float* out = (float*)d_out;

    int total_values = in_sizes[0];     // 17,301,504
    int num_rows     = in_sizes[1];     // 1,048,576
    int n_quads      = num_rows * (DIM / 4);   // one thread per float4

    const int block = 256;
    int grid = (n_quads + block - 1) / block;
    ragged_to_dense_kernel<<<grid, block, 0, stream>>>(
        values, offsets, out, num_rows, total_values);
}